// Round 4
// baseline (164.656 us; speedup 1.0000x reference)
//
#include <hip/hip_runtime.h>
#include <math.h>

#define KCONST 0.1f
#define GAMMA_C 1.0f
#define D_DIM 128

typedef __attribute__((ext_vector_type(8))) short bf16x8;
typedef __attribute__((ext_vector_type(4))) float f32x4;

#define ASYNC_COPY16(gsrc, ldst)                                                  \
  __builtin_amdgcn_global_load_lds(                                               \
      (const __attribute__((address_space(1))) void*)(gsrc),                      \
      (__attribute__((address_space(3))) void*)(ldst), 16, 0, 0)

__device__ __forceinline__ unsigned short f2bf(float f) {
  unsigned int u = __float_as_uint(f);
  u += 0x7fffu + ((u >> 16) & 1u);  // round-to-nearest-even
  return (unsigned short)(u >> 16);
}

// ---------------------------------------------------------------------------
// prep_x: 256 blocks. 16 lanes per row, 4 rows per wave-iteration, 4 iters.
// Converts x->bf16, writes nx2[row], per-block partial col-sums + sum(nx2)
// (plain stores -- no global atomics).
// ---------------------------------------------------------------------------
__global__ void prep_x(const float* __restrict__ x, unsigned short* __restrict__ xb,
                       float* __restrict__ nx2, float* __restrict__ pSumX,
                       float* __restrict__ pS2, int N) {
  const int tid = threadIdx.x;
  const int l = tid & 63, w = tid >> 6;
  const int l16 = l & 15, sub = l >> 4;
  const int waveId = blockIdx.x * 4 + w;  // 0..1023
  const float4* x4 = (const float4*)x;
  ushort4* xb4 = (ushort4*)xb;
  float4 c0 = {0.f, 0.f, 0.f, 0.f}, c1 = {0.f, 0.f, 0.f, 0.f};
  float s2 = 0.f;
#pragma unroll
  for (int it = 0; it < 4; ++it) {
    int row = (waveId + it * 1024) * 4 + sub;
    float4 v0 = x4[row * 32 + l16];
    float4 v1 = x4[row * 32 + 16 + l16];
    c0.x += v0.x; c0.y += v0.y; c0.z += v0.z; c0.w += v0.w;
    c1.x += v1.x; c1.y += v1.y; c1.z += v1.z; c1.w += v1.w;
    ushort4 b0, b1;
    b0.x = f2bf(v0.x); b0.y = f2bf(v0.y); b0.z = f2bf(v0.z); b0.w = f2bf(v0.w);
    b1.x = f2bf(v1.x); b1.y = f2bf(v1.y); b1.z = f2bf(v1.z); b1.w = f2bf(v1.w);
    xb4[row * 32 + l16] = b0;
    xb4[row * 32 + 16 + l16] = b1;
    float sq = v0.x * v0.x;
    sq = fmaf(v0.y, v0.y, sq); sq = fmaf(v0.z, v0.z, sq); sq = fmaf(v0.w, v0.w, sq);
    sq = fmaf(v1.x, v1.x, sq); sq = fmaf(v1.y, v1.y, sq);
    sq = fmaf(v1.z, v1.z, sq); sq = fmaf(v1.w, v1.w, sq);
    sq += __shfl_down(sq, 8); sq += __shfl_down(sq, 4);
    sq += __shfl_down(sq, 2); sq += __shfl_down(sq, 1);
    if (l16 == 0) {
      nx2[row] = sq;
      s2 += sq;
    }
  }
  // s2 lives at lanes {0,16,32,48}
  s2 += __shfl_down(s2, 16);
  s2 += __shfl_down(s2, 32);
  __shared__ float cs[128];
  __shared__ float s2w[4];
  if (tid < 128) cs[tid] = 0.f;
  if (l == 0) s2w[w] = s2;
  __syncthreads();
  atomicAdd(&cs[l16 * 4 + 0], c0.x); atomicAdd(&cs[l16 * 4 + 1], c0.y);
  atomicAdd(&cs[l16 * 4 + 2], c0.z); atomicAdd(&cs[l16 * 4 + 3], c0.w);
  atomicAdd(&cs[64 + l16 * 4 + 0], c1.x); atomicAdd(&cs[64 + l16 * 4 + 1], c1.y);
  atomicAdd(&cs[64 + l16 * 4 + 2], c1.z); atomicAdd(&cs[64 + l16 * 4 + 3], c1.w);
  __syncthreads();
  if (tid < 128) pSumX[blockIdx.x * 128 + tid] = cs[tid];
  if (tid == 0) pS2[blockIdx.x] = s2w[0] + s2w[1] + s2w[2] + s2w[3];
}

// ---------------------------------------------------------------------------
// merge: 1 block. sum_x[c] = sum over 256 block partials; sum_nx2 likewise.
// ---------------------------------------------------------------------------
__global__ void merge_sums(const float* __restrict__ pSumX, const float* __restrict__ pS2,
                           float* __restrict__ sum_x, float* __restrict__ sum_nx2,
                           int nb) {
  const int t = threadIdx.x;
  if (t < 128) {
    float s = 0.f;
    for (int b = 0; b < nb; ++b) s += pSumX[b * 128 + t];
    sum_x[t] = s;
  }
  float s2 = (t < nb) ? pS2[t] : 0.f;
#pragma unroll
  for (int off = 32; off; off >>= 1) s2 += __shfl_down(s2, off);
  __shared__ float wred[4];
  if ((t & 63) == 0) wred[t >> 6] = s2;
  __syncthreads();
  if (t == 0) sum_nx2[0] = wred[0] + wred[1] + wred[2] + wred[3];
}

// ---------------------------------------------------------------------------
// prep_p: wave-per-row. Converts p->bf16; packs colc[j] =
// (Ac=(1+np2)*cfi, Bc=np2*cfi, np2, C1=1+psi).
// ---------------------------------------------------------------------------
__global__ void prep_p(const float* __restrict__ p, unsigned short* __restrict__ pb,
                       const float* __restrict__ sum_x, const float* __restrict__ sum_nx2,
                       float4* __restrict__ colc, int M, int N) {
  const int lane = threadIdx.x & 63;
  const int wave = threadIdx.x >> 6;
  const int j = blockIdx.x * 4 + wave;
  if (j >= M) return;
  const float2* p2 = (const float2*)p;
  ushort2* pb2 = (ushort2*)pb;
  float2 v = p2[j * 64 + lane];
  ushort2 b;
  b.x = f2bf(v.x);
  b.y = f2bf(v.y);
  pb2[j * 64 + lane] = b;
  float np2 = fmaf(v.x, v.x, v.y * v.y);
  float sd = fmaf(v.x, sum_x[2 * lane], v.y * sum_x[2 * lane + 1]);
#pragma unroll
  for (int off = 32; off; off >>= 1) {
    np2 += __shfl_down(np2, off);
    sd += __shfl_down(sd, off);
  }
  if (lane == 0) {
    float ssd = *sum_nx2 + (float)N * np2 - 2.f * sd;
    float npn = sqrtf(np2);
    float cfi = 1.f / (npn * sqrtf(ssd));
    float4 cc;
    cc.x = (1.f + np2) * cfi;
    cc.y = np2 * cfi;
    cc.z = np2;
    cc.w = 1.f + asinf(KCONST * (1.f - np2) / npn);
    colc[j] = cc;
  }
}

// ---------------------------------------------------------------------------
// corr: per-row label correction: sum over rows of (pos - neg) at the label
// column, computed in fp32. 256 blocks, 16 lanes/row, 4 rows/wave, 4 iters.
// ---------------------------------------------------------------------------
__global__ void corr_kernel(const float* __restrict__ x, const float* __restrict__ p,
                            const int* __restrict__ labels, const float* __restrict__ nx2,
                            const float4* __restrict__ colc,
                            float* __restrict__ partials, int N) {
  const int tid = threadIdx.x;
  const int l = tid & 63, w = tid >> 6;
  const int l16 = l & 15, sub = l >> 4;
  const int waveId = blockIdx.x * 4 + w;
  const float4* x4 = (const float4*)x;
  const float4* p4 = (const float4*)p;
  float s = 0.f;
#pragma unroll
  for (int it = 0; it < 4; ++it) {
    int row = (waveId + it * 1024) * 4 + sub;
    int lab = labels[row];
    float4 a0 = x4[row * 32 + l16], a1 = x4[row * 32 + 16 + l16];
    float4 b0 = p4[lab * 32 + l16], b1 = p4[lab * 32 + 16 + l16];
    float d = a0.x * b0.x;
    d = fmaf(a0.y, b0.y, d); d = fmaf(a0.z, b0.z, d); d = fmaf(a0.w, b0.w, d);
    d = fmaf(a1.x, b1.x, d); d = fmaf(a1.y, b1.y, d);
    d = fmaf(a1.z, b1.z, d); d = fmaf(a1.w, b1.w, d);
    d += __shfl_down(d, 8); d += __shfl_down(d, 4);
    d += __shfl_down(d, 2); d += __shfl_down(d, 1);
    if (l16 == 0) {
      float rn = nx2[row];
      float4 cc = colc[lab];
      float den2 = fmaf(-2.f, d, fmaf(cc.z, rn, 1.f));
      float nump = fmaf(d, cc.x, -fmaf(cc.y, rn, cc.y));
      float u = nump * __builtin_amdgcn_rsqf(den2);
      u = fminf(1.f, fmaxf(-1.f, u));
      float ac = acosf(u);
      float psi = cc.w - 1.f;
      float pos = fmaxf(0.f, ac - psi);
      float neg = __builtin_amdgcn_fmed3f(cc.w - ac, 0.f, 1.f);
      s += pos - neg;
    }
  }
#pragma unroll
  for (int off = 32; off; off >>= 1) s += __shfl_down(s, off);
  __shared__ float wred[4];
  if (l == 0) wred[w] = s;
  __syncthreads();
  if (tid == 0) partials[blockIdx.x] = wred[0] + wred[1] + wred[2] + wred[3];
}

// ---------------------------------------------------------------------------
// pair_mfma: 128x128 tile/block; 4 waves in 2x2, each 64x64 (64 MFMA).
// Staging via global_load_lds width=16 with XOR-swizzled SOURCE permutation
// (LDS side is lane-contiguous by HW), unpadded 64 KB LDS.
// Epilogue: med3 negative-loss form, deg-3 acos (no sign flip needed), no
// label compare (handled by corr_kernel). Plain-store block partial.
// ---------------------------------------------------------------------------
__global__ __launch_bounds__(256, 2) void pair_mfma(
    const unsigned short* __restrict__ xb, const unsigned short* __restrict__ pb,
    const float* __restrict__ nx2, const float4* __restrict__ colc,
    float* __restrict__ partials) {
  __shared__ float4 xs4[2048];  // 128 rows x 16 quads (quad = 8 bf16)
  __shared__ float4 ps4[2048];
  __shared__ float nxs[128];
  __shared__ float wred[4];

  const int tid = threadIdx.x;
  const int l = tid & 63;
  const int w = tid >> 6;
  const int row0 = blockIdx.y * 128;
  const int col0 = blockIdx.x * 128;
  const float4* xg = (const float4*)(xb + (size_t)row0 * D_DIM);
  const float4* pg = (const float4*)(pb + (size_t)col0 * D_DIM);

  // stage A+B: 32 wave-issues each of 64 quads; LDS slot (r,ql) holds source
  // quad (r, ql ^ (r&15))
#pragma unroll
  for (int ci = w; ci < 32; ci += 4) {
    int qi = ci * 64 + l;
    int r = qi >> 4, ql = qi & 15;
    int srcq = r * 16 + (ql ^ (r & 15));
    ASYNC_COPY16(xg + srcq, xs4 + ci * 64);
    ASYNC_COPY16(pg + srcq, ps4 + ci * 64);
  }
  if (tid < 128) nxs[tid] = nx2[row0 + tid];
  __syncthreads();

  const int m = tid & 15;
  const int q = (tid >> 4) & 3;
  const int wr = (w & 1) * 64;   // wave's row offset within tile
  const int wc = (w >> 1) * 64;  // wave's col offset within tile

  f32x4 acc[4][4];
#pragma unroll
  for (int r = 0; r < 4; ++r)
#pragma unroll
    for (int c = 0; c < 4; ++c) acc[r][c] = (f32x4)(0.f);

#pragma unroll
  for (int s = 0; s < 4; ++s) {
    const int qphys = (s * 4 + q) ^ m;  // logical quad s*4+q, row low bits = m
    bf16x8 a[4], b[4];
#pragma unroll
    for (int r = 0; r < 4; ++r) {
      a[r] = __builtin_bit_cast(bf16x8, xs4[(wr + r * 16 + m) * 16 + qphys]);
      b[r] = __builtin_bit_cast(bf16x8, ps4[(wc + r * 16 + m) * 16 + qphys]);
    }
#pragma unroll
    for (int r = 0; r < 4; ++r)
#pragma unroll
      for (int c = 0; c < 4; ++c)
        acc[r][c] = __builtin_amdgcn_mfma_f32_16x16x32_bf16(a[r], b[c], acc[r][c], 0, 0, 0);
  }

  // ---- fused epilogue ----
  float4 cc[4];
#pragma unroll
  for (int c = 0; c < 4; ++c) cc[c] = colc[col0 + wc + c * 16 + m];

  float ssum = 0.f;
#pragma unroll
  for (int r = 0; r < 4; ++r) {
    const f32x4 rn4 = __builtin_bit_cast(f32x4, *(const float4*)&nxs[wr + r * 16 + q * 4]);
#pragma unroll
    for (int c = 0; c < 4; ++c) {
#pragma unroll
      for (int g = 0; g < 4; ++g) {
        float rn = rn4[g];
        float dot = acc[r][c][g];
        float den2 = fmaf(-2.f, dot, fmaf(cc[c].z, rn, 1.f));
        float nump = fmaf(dot, cc[c].x, -fmaf(cc[c].y, rn, cc[c].y));
        float u = nump * __builtin_amdgcn_rsqf(den2);
        u = fminf(u, 1.f);
        float rt = __builtin_amdgcn_sqrtf(1.f - u);
        float poly = fmaf(fmaf(fmaf(-0.0187293f, u, 0.0742610f), u, -0.2121144f),
                          u, 1.5707288f);
        float ac = rt * poly;  // acos approx, valid u in [0,1]; >1.31 for u<0.26
        ssum += __builtin_amdgcn_fmed3f(cc[c].w - ac, 0.f, 1.f);
      }
    }
  }

#pragma unroll
  for (int off = 32; off; off >>= 1) ssum += __shfl_down(ssum, off);
  if (l == 0) wred[w] = ssum;
  __syncthreads();
  if (tid == 0)
    partials[blockIdx.y * gridDim.x + blockIdx.x] = wred[0] + wred[1] + wred[2] + wred[3];
}

// ---------------------------------------------------------------------------
// finalize: reduce all partials (corr 256 + pair 2048), scale by 1/N.
// ---------------------------------------------------------------------------
__global__ void finalize(const float* __restrict__ partials, float* __restrict__ out,
                         int n, float invN) {
  float s = 0.f;
  for (int i = threadIdx.x; i < n; i += 256) s += partials[i];
#pragma unroll
  for (int off = 32; off; off >>= 1) s += __shfl_down(s, off);
  __shared__ float wred[4];
  if ((threadIdx.x & 63) == 0) wred[threadIdx.x >> 6] = s;
  __syncthreads();
  if (threadIdx.x == 0) out[0] = (wred[0] + wred[1] + wred[2] + wred[3]) * invN;
}

extern "C" void kernel_launch(void* const* d_in, const int* in_sizes, int n_in,
                              void* d_out, int out_size, void* d_ws, size_t ws_size,
                              hipStream_t stream) {
  const float* x = (const float*)d_in[0];
  const float* p = (const float*)d_in[1];
  const int* labels = (const int*)d_in[2];
  float* out = (float*)d_out;
  const int N = in_sizes[2];          // 16384
  const int M = in_sizes[1] / D_DIM;  // 2048

  float* ws = (float*)d_ws;
  float* nx2 = ws;                                   // N
  float4* colc = (float4*)(ws + N);                  // M float4
  unsigned short* xb = (unsigned short*)(ws + N + 4 * M);            // N*128 bf16
  unsigned short* pb = (unsigned short*)(ws + N + 4 * M + 64 * N);   // M*128 bf16
  float* pSumX = ws + N + 4 * M + 64 * N + 64 * M;   // 256*128
  float* pS2 = pSumX + 256 * 128;                    // 256
  float* sum_x = pS2 + 256;                          // 128
  float* sum_nx2 = sum_x + 128;                      // 4
  float* partials = sum_nx2 + 4;                     // 256 + 2048

  prep_x<<<256, 256, 0, stream>>>(x, xb, nx2, pSumX, pS2, N);
  merge_sums<<<1, 256, 0, stream>>>(pSumX, pS2, sum_x, sum_nx2, 256);
  prep_p<<<M / 4, 256, 0, stream>>>(p, pb, sum_x, sum_nx2, colc, M, N);
  corr_kernel<<<256, 256, 0, stream>>>(x, p, labels, nx2, colc, partials, N);

  dim3 grid(M / 128, N / 128);
  pair_mfma<<<grid, 256, 0, stream>>>(xb, pb, nx2, colc, partials + 256);

  finalize<<<1, 256, 0, stream>>>(partials, out, 256 + 2048, 1.0f / (float)N);
}

// Round 6
// 102.626 us; speedup vs baseline: 1.6044x; 1.6044x over previous
//
#include <hip/hip_runtime.h>
#include <math.h>

#define KCONST 0.1f
#define GAMMA_C 1.0f
#define D_DIM 128

typedef __attribute__((ext_vector_type(8))) short bf16x8;
typedef __attribute__((ext_vector_type(4))) float f32x4;

#define ASYNC_COPY16(gsrc, ldst)                                                  \
  __builtin_amdgcn_global_load_lds(                                               \
      (const __attribute__((address_space(1))) void*)(gsrc),                      \
      (__attribute__((address_space(3))) void*)(ldst), 16, 0, 0)

__device__ __forceinline__ unsigned short f2bf(float f) {
  unsigned int u = __float_as_uint(f);
  u += 0x7fffu + ((u >> 16) & 1u);  // round-to-nearest-even
  return (unsigned short)(u >> 16);
}

// ---------------------------------------------------------------------------
// prep_x: 256 blocks. 16 lanes per row, 4 rows per wave-iteration, 4 iters.
// Converts x->bf16, writes nx2[row], per-block partial col-sums + sum(nx2)
// (plain stores -- no global atomics).
// ---------------------------------------------------------------------------
__global__ void prep_x(const float* __restrict__ x, unsigned short* __restrict__ xb,
                       float* __restrict__ nx2, float* __restrict__ pSumX,
                       float* __restrict__ pS2, int N) {
  const int tid = threadIdx.x;
  const int l = tid & 63, w = tid >> 6;
  const int l16 = l & 15, sub = l >> 4;
  const int waveId = blockIdx.x * 4 + w;  // 0..1023
  const float4* x4 = (const float4*)x;
  ushort4* xb4 = (ushort4*)xb;
  float4 c0 = {0.f, 0.f, 0.f, 0.f}, c1 = {0.f, 0.f, 0.f, 0.f};
  float s2 = 0.f;
#pragma unroll
  for (int it = 0; it < 4; ++it) {
    int row = (waveId + it * 1024) * 4 + sub;
    float4 v0 = x4[row * 32 + l16];
    float4 v1 = x4[row * 32 + 16 + l16];
    c0.x += v0.x; c0.y += v0.y; c0.z += v0.z; c0.w += v0.w;
    c1.x += v1.x; c1.y += v1.y; c1.z += v1.z; c1.w += v1.w;
    ushort4 b0, b1;
    b0.x = f2bf(v0.x); b0.y = f2bf(v0.y); b0.z = f2bf(v0.z); b0.w = f2bf(v0.w);
    b1.x = f2bf(v1.x); b1.y = f2bf(v1.y); b1.z = f2bf(v1.z); b1.w = f2bf(v1.w);
    xb4[row * 32 + l16] = b0;
    xb4[row * 32 + 16 + l16] = b1;
    float sq = v0.x * v0.x;
    sq = fmaf(v0.y, v0.y, sq); sq = fmaf(v0.z, v0.z, sq); sq = fmaf(v0.w, v0.w, sq);
    sq = fmaf(v1.x, v1.x, sq); sq = fmaf(v1.y, v1.y, sq);
    sq = fmaf(v1.z, v1.z, sq); sq = fmaf(v1.w, v1.w, sq);
    sq += __shfl_down(sq, 8); sq += __shfl_down(sq, 4);
    sq += __shfl_down(sq, 2); sq += __shfl_down(sq, 1);
    if (l16 == 0) {
      nx2[row] = sq;
      s2 += sq;
    }
  }
  // s2 lives at lanes {0,16,32,48}
  s2 += __shfl_down(s2, 16);
  s2 += __shfl_down(s2, 32);
  __shared__ float cs[128];
  __shared__ float s2w[4];
  if (tid < 128) cs[tid] = 0.f;
  if (l == 0) s2w[w] = s2;
  __syncthreads();
  atomicAdd(&cs[l16 * 4 + 0], c0.x); atomicAdd(&cs[l16 * 4 + 1], c0.y);
  atomicAdd(&cs[l16 * 4 + 2], c0.z); atomicAdd(&cs[l16 * 4 + 3], c0.w);
  atomicAdd(&cs[64 + l16 * 4 + 0], c1.x); atomicAdd(&cs[64 + l16 * 4 + 1], c1.y);
  atomicAdd(&cs[64 + l16 * 4 + 2], c1.z); atomicAdd(&cs[64 + l16 * 4 + 3], c1.w);
  __syncthreads();
  if (tid < 128) pSumX[blockIdx.x * 128 + tid] = cs[tid];
  if (tid == 0) pS2[blockIdx.x] = s2w[0] + s2w[1] + s2w[2] + s2w[3];
}

// ---------------------------------------------------------------------------
// merge_sums: 1 block x 1024 threads (16 waves for latency hiding).
// thread = (seg 0..7, col 0..127); 32 fully-unrolled independent loads each
// (memory-level parallelism), LDS combine of the 8 segment partials.
// ---------------------------------------------------------------------------
__global__ void merge_sums(const float* __restrict__ pSumX, const float* __restrict__ pS2,
                           float* __restrict__ sum_x, float* __restrict__ sum_nx2) {
  __shared__ float seg[8][128];
  __shared__ float s2w[4];
  const int t = threadIdx.x;       // 0..1023
  const int col = t & 127;
  const int sg = t >> 7;           // 0..7
  float s = 0.f;
#pragma unroll
  for (int b = 0; b < 32; ++b) s += pSumX[(sg * 32 + b) * 128 + col];
  seg[sg][col] = s;
  float s2 = (t < 256) ? pS2[t] : 0.f;
  if (t < 256) {
#pragma unroll
    for (int off = 32; off; off >>= 1) s2 += __shfl_down(s2, off);
    if ((t & 63) == 0) s2w[t >> 6] = s2;
  }
  __syncthreads();
  if (t < 128) {
    float r = 0.f;
#pragma unroll
    for (int k = 0; k < 8; ++k) r += seg[k][col];
    sum_x[t] = r;
  }
  if (t == 0) sum_nx2[0] = s2w[0] + s2w[1] + s2w[2] + s2w[3];
}

// ---------------------------------------------------------------------------
// prep_p: wave-per-row. Converts p->bf16; packs colc[j] =
// (Ac=(1+np2)*cfi, Bc=np2*cfi, np2, C1=1+psi).
// ---------------------------------------------------------------------------
__global__ void prep_p(const float* __restrict__ p, unsigned short* __restrict__ pb,
                       const float* __restrict__ sum_x, const float* __restrict__ sum_nx2,
                       float4* __restrict__ colc, int M, int N) {
  const int lane = threadIdx.x & 63;
  const int wave = threadIdx.x >> 6;
  const int j = blockIdx.x * 4 + wave;
  if (j >= M) return;
  const float2* p2 = (const float2*)p;
  ushort2* pb2 = (ushort2*)pb;
  float2 v = p2[j * 64 + lane];
  ushort2 b;
  b.x = f2bf(v.x);
  b.y = f2bf(v.y);
  pb2[j * 64 + lane] = b;
  float np2 = fmaf(v.x, v.x, v.y * v.y);
  float sd = fmaf(v.x, sum_x[2 * lane], v.y * sum_x[2 * lane + 1]);
#pragma unroll
  for (int off = 32; off; off >>= 1) {
    np2 += __shfl_down(np2, off);
    sd += __shfl_down(sd, off);
  }
  if (lane == 0) {
    float ssd = *sum_nx2 + (float)N * np2 - 2.f * sd;
    float npn = sqrtf(np2);
    float cfi = 1.f / (npn * sqrtf(ssd));
    float4 cc;
    cc.x = (1.f + np2) * cfi;
    cc.y = np2 * cfi;
    cc.z = np2;
    cc.w = 1.f + asinf(KCONST * (1.f - np2) / npn);
    colc[j] = cc;
  }
}

// ---------------------------------------------------------------------------
// pair_mfma: 128x128 tile/block; 4 waves in 2x2, each 64x64 (64 MFMA).
// Staging via global_load_lds width=16 with XOR-swizzled SOURCE permutation.
// Epilogue: med3 negative form for ALL elements; label column handled by a
// rare exec-masked branch (expected ~8 hits / 16K elements per block) that
// adds (pos - neg) using a sign-corrected deg-3 acos. Plain-store partial.
// ---------------------------------------------------------------------------
__global__ __launch_bounds__(256, 2) void pair_mfma(
    const unsigned short* __restrict__ xb, const unsigned short* __restrict__ pb,
    const int* __restrict__ labels, const float* __restrict__ nx2,
    const float4* __restrict__ colc, float* __restrict__ partials) {
  __shared__ float4 xs4[2048];  // 128 rows x 16 quads (quad = 8 bf16)
  __shared__ float4 ps4[2048];
  __shared__ float nxs[128];
  __shared__ int lbs[128];
  __shared__ float wred[4];

  const int tid = threadIdx.x;
  const int l = tid & 63;
  const int w = tid >> 6;
  const int row0 = blockIdx.y * 128;
  const int col0 = blockIdx.x * 128;
  const float4* xg = (const float4*)(xb + (size_t)row0 * D_DIM);
  const float4* pg = (const float4*)(pb + (size_t)col0 * D_DIM);

  // stage A+B: LDS slot (r,ql) holds source quad (r, ql ^ (r&15))
#pragma unroll
  for (int ci = w; ci < 32; ci += 4) {
    int qi = ci * 64 + l;
    int r = qi >> 4, ql = qi & 15;
    int srcq = r * 16 + (ql ^ (r & 15));
    ASYNC_COPY16(xg + srcq, xs4 + ci * 64);
    ASYNC_COPY16(pg + srcq, ps4 + ci * 64);
  }
  if (tid < 128) {
    nxs[tid] = nx2[row0 + tid];
    lbs[tid] = labels[row0 + tid];
  }
  __syncthreads();

  const int m = tid & 15;
  const int q = (tid >> 4) & 3;
  const int wr = (w & 1) * 64;   // wave's row offset within tile
  const int wc = (w >> 1) * 64;  // wave's col offset within tile

  f32x4 acc[4][4];
#pragma unroll
  for (int r = 0; r < 4; ++r)
#pragma unroll
    for (int c = 0; c < 4; ++c) acc[r][c] = (f32x4)(0.f);

#pragma unroll
  for (int s = 0; s < 4; ++s) {
    const int qphys = (s * 4 + q) ^ m;  // logical quad s*4+q, row low bits = m
    bf16x8 a[4], b[4];
#pragma unroll
    for (int r = 0; r < 4; ++r) {
      a[r] = __builtin_bit_cast(bf16x8, xs4[(wr + r * 16 + m) * 16 + qphys]);
      b[r] = __builtin_bit_cast(bf16x8, ps4[(wc + r * 16 + m) * 16 + qphys]);
    }
#pragma unroll
    for (int r = 0; r < 4; ++r)
#pragma unroll
      for (int c = 0; c < 4; ++c)
        acc[r][c] = __builtin_amdgcn_mfma_f32_16x16x32_bf16(a[r], b[c], acc[r][c], 0, 0, 0);
  }

  // ---- fused epilogue ----
  float4 cc[4];
  int cols[4];
#pragma unroll
  for (int c = 0; c < 4; ++c) {
    cols[c] = col0 + wc + c * 16 + m;
    cc[c] = colc[cols[c]];
  }

  float ssum = 0.f;
#pragma unroll
  for (int r = 0; r < 4; ++r) {
    const f32x4 rn4 = __builtin_bit_cast(f32x4, *(const float4*)&nxs[wr + r * 16 + q * 4]);
    const int4 lb4 = *(const int4*)&lbs[wr + r * 16 + q * 4];
#pragma unroll
    for (int c = 0; c < 4; ++c) {
#pragma unroll
      for (int g = 0; g < 4; ++g) {
        float rn = rn4[g];
        int lb = (g == 0) ? lb4.x : (g == 1) ? lb4.y : (g == 2) ? lb4.z : lb4.w;
        float dot = acc[r][c][g];
        float den2 = fmaf(-2.f, dot, fmaf(cc[c].z, rn, 1.f));
        float nump = fmaf(dot, cc[c].x, -fmaf(cc[c].y, rn, cc[c].y));
        float u = nump * __builtin_amdgcn_rsqf(den2);
        u = fminf(u, 1.f);
        float rt = __builtin_amdgcn_sqrtf(1.f - u);
        float poly = fmaf(fmaf(fmaf(-0.0187293f, u, 0.0742610f), u, -0.2121144f),
                          u, 1.5707288f);
        float ac = rt * poly;  // acos approx; for u<cos(C1) it stays >= C1
        float neg = __builtin_amdgcn_fmed3f(cc[c].w - ac, 0.f, 1.f);
        ssum += neg;
        if (__builtin_expect(cols[c] == lb, 0)) {
          // rare: label column -> exact-enough full-range acos
          float uc = fmaxf(u, -1.f);
          float ax = fabsf(uc);
          float rt2 = __builtin_amdgcn_sqrtf(1.f - ax);
          float p2 = fmaf(fmaf(fmaf(-0.0187293f, ax, 0.0742610f), ax, -0.2121144f),
                          ax, 1.5707288f);
          float ac2 = rt2 * p2;
          ac2 = (uc >= 0.f) ? ac2 : 3.14159265358979f - ac2;
          float pos = fmaxf(0.f, ac2 - (cc[c].w - 1.f));
          ssum += pos - neg;
        }
      }
    }
  }

#pragma unroll
  for (int off = 32; off; off >>= 1) ssum += __shfl_down(ssum, off);
  if (l == 0) wred[w] = ssum;
  __syncthreads();
  if (tid == 0)
    partials[blockIdx.y * gridDim.x + blockIdx.x] = wred[0] + wred[1] + wred[2] + wred[3];
}

// ---------------------------------------------------------------------------
// finalize: reduce the 2048 pair partials, scale by 1/N.
// ---------------------------------------------------------------------------
__global__ void finalize(const float* __restrict__ partials, float* __restrict__ out,
                         int n, float invN) {
  float s = 0.f;
  for (int i = threadIdx.x; i < n; i += 256) s += partials[i];
#pragma unroll
  for (int off = 32; off; off >>= 1) s += __shfl_down(s, off);
  __shared__ float wred[4];
  if ((threadIdx.x & 63) == 0) wred[threadIdx.x >> 6] = s;
  __syncthreads();
  if (threadIdx.x == 0) out[0] = (wred[0] + wred[1] + wred[2] + wred[3]) * invN;
}

extern "C" void kernel_launch(void* const* d_in, const int* in_sizes, int n_in,
                              void* d_out, int out_size, void* d_ws, size_t ws_size,
                              hipStream_t stream) {
  const float* x = (const float*)d_in[0];
  const float* p = (const float*)d_in[1];
  const int* labels = (const int*)d_in[2];
  float* out = (float*)d_out;
  const int N = in_sizes[2];          // 16384
  const int M = in_sizes[1] / D_DIM;  // 2048

  float* ws = (float*)d_ws;
  float* nx2 = ws;                                   // N
  float4* colc = (float4*)(ws + N);                  // M float4
  unsigned short* xb = (unsigned short*)(ws + N + 4 * M);            // N*128 bf16
  unsigned short* pb = (unsigned short*)(ws + N + 4 * M + 64 * N);   // M*128 bf16
  float* pSumX = ws + N + 4 * M + 64 * N + 64 * M;   // 256*128
  float* pS2 = pSumX + 256 * 128;                    // 256
  float* sum_x = pS2 + 256;                          // 128
  float* sum_nx2 = sum_x + 128;                      // 4
  float* partials = sum_nx2 + 4;                     // 2048

  prep_x<<<256, 256, 0, stream>>>(x, xb, nx2, pSumX, pS2, N);
  merge_sums<<<1, 1024, 0, stream>>>(pSumX, pS2, sum_x, sum_nx2);
  prep_p<<<M / 4, 256, 0, stream>>>(p, pb, sum_x, sum_nx2, colc, M, N);

  dim3 grid(M / 128, N / 128);
  pair_mfma<<<grid, 256, 0, stream>>>(xb, pb, labels, nx2, colc, partials);

  finalize<<<1, 256, 0, stream>>>(partials, out, 2048, 1.0f / (float)N);
}

// Round 7
// 96.570 us; speedup vs baseline: 1.7050x; 1.0627x over previous
//
#include <hip/hip_runtime.h>
#include <math.h>

#define KCONST 0.1f
#define GAMMA_C 1.0f
#define D_DIM 128

typedef __attribute__((ext_vector_type(8))) short bf16x8;
typedef __attribute__((ext_vector_type(4))) float f32x4;

#define ASYNC_COPY16(gsrc, ldst)                                                  \
  __builtin_amdgcn_global_load_lds(                                               \
      (const __attribute__((address_space(1))) void*)(gsrc),                      \
      (__attribute__((address_space(3))) void*)(ldst), 16, 0, 0)

__device__ __forceinline__ unsigned short f2bf(float f) {
  unsigned int u = __float_as_uint(f);
  u += 0x7fffu + ((u >> 16) & 1u);  // round-to-nearest-even
  return (unsigned short)(u >> 16);
}

// ---------------------------------------------------------------------------
// prep_x: 256 blocks. 16 lanes per row, 4 rows per wave-iteration, 4 iters.
// Converts x->bf16, writes nx2[row], per-block partial col-sums + sum(nx2).
// ---------------------------------------------------------------------------
__global__ void prep_x(const float* __restrict__ x, unsigned short* __restrict__ xb,
                       float* __restrict__ nx2, float* __restrict__ pSumX,
                       float* __restrict__ pS2, int N) {
  const int tid = threadIdx.x;
  const int l = tid & 63, w = tid >> 6;
  const int l16 = l & 15, sub = l >> 4;
  const int waveId = blockIdx.x * 4 + w;  // 0..1023
  const float4* x4 = (const float4*)x;
  ushort4* xb4 = (ushort4*)xb;
  float4 c0 = {0.f, 0.f, 0.f, 0.f}, c1 = {0.f, 0.f, 0.f, 0.f};
  float s2 = 0.f;
#pragma unroll
  for (int it = 0; it < 4; ++it) {
    int row = (waveId + it * 1024) * 4 + sub;
    float4 v0 = x4[row * 32 + l16];
    float4 v1 = x4[row * 32 + 16 + l16];
    c0.x += v0.x; c0.y += v0.y; c0.z += v0.z; c0.w += v0.w;
    c1.x += v1.x; c1.y += v1.y; c1.z += v1.z; c1.w += v1.w;
    ushort4 b0, b1;
    b0.x = f2bf(v0.x); b0.y = f2bf(v0.y); b0.z = f2bf(v0.z); b0.w = f2bf(v0.w);
    b1.x = f2bf(v1.x); b1.y = f2bf(v1.y); b1.z = f2bf(v1.z); b1.w = f2bf(v1.w);
    xb4[row * 32 + l16] = b0;
    xb4[row * 32 + 16 + l16] = b1;
    float sq = v0.x * v0.x;
    sq = fmaf(v0.y, v0.y, sq); sq = fmaf(v0.z, v0.z, sq); sq = fmaf(v0.w, v0.w, sq);
    sq = fmaf(v1.x, v1.x, sq); sq = fmaf(v1.y, v1.y, sq);
    sq = fmaf(v1.z, v1.z, sq); sq = fmaf(v1.w, v1.w, sq);
    sq += __shfl_down(sq, 8); sq += __shfl_down(sq, 4);
    sq += __shfl_down(sq, 2); sq += __shfl_down(sq, 1);
    if (l16 == 0) {
      nx2[row] = sq;
      s2 += sq;
    }
  }
  // s2 lives at lanes {0,16,32,48}
  s2 += __shfl_down(s2, 16);
  s2 += __shfl_down(s2, 32);
  __shared__ float cs[128];
  __shared__ float s2w[4];
  if (tid < 128) cs[tid] = 0.f;
  if (l == 0) s2w[w] = s2;
  __syncthreads();
  atomicAdd(&cs[l16 * 4 + 0], c0.x); atomicAdd(&cs[l16 * 4 + 1], c0.y);
  atomicAdd(&cs[l16 * 4 + 2], c0.z); atomicAdd(&cs[l16 * 4 + 3], c0.w);
  atomicAdd(&cs[64 + l16 * 4 + 0], c1.x); atomicAdd(&cs[64 + l16 * 4 + 1], c1.y);
  atomicAdd(&cs[64 + l16 * 4 + 2], c1.z); atomicAdd(&cs[64 + l16 * 4 + 3], c1.w);
  __syncthreads();
  if (tid < 128) pSumX[blockIdx.x * 128 + tid] = cs[tid];
  if (tid == 0) pS2[blockIdx.x] = s2w[0] + s2w[1] + s2w[2] + s2w[3];
}

// ---------------------------------------------------------------------------
// merge_sums: 1 block x 1024 threads; 8-way segmented unrolled loads (MLP).
// ---------------------------------------------------------------------------
__global__ void merge_sums(const float* __restrict__ pSumX, const float* __restrict__ pS2,
                           float* __restrict__ sum_x, float* __restrict__ sum_nx2) {
  __shared__ float seg[8][128];
  __shared__ float s2w[4];
  const int t = threadIdx.x;       // 0..1023
  const int col = t & 127;
  const int sg = t >> 7;           // 0..7
  float s = 0.f;
#pragma unroll
  for (int b = 0; b < 32; ++b) s += pSumX[(sg * 32 + b) * 128 + col];
  seg[sg][col] = s;
  float s2 = (t < 256) ? pS2[t] : 0.f;
  if (t < 256) {
#pragma unroll
    for (int off = 32; off; off >>= 1) s2 += __shfl_down(s2, off);
    if ((t & 63) == 0) s2w[t >> 6] = s2;
  }
  __syncthreads();
  if (t < 128) {
    float r = 0.f;
#pragma unroll
    for (int k = 0; k < 8; ++k) r += seg[k][col];
    sum_x[t] = r;
  }
  if (t == 0) sum_nx2[0] = s2w[0] + s2w[1] + s2w[2] + s2w[3];
}

// ---------------------------------------------------------------------------
// prep_p: wave-per-row. Converts p->bf16; packs colc[j] =
// (Ac=(1+np2)*cfi, Bc=np2*cfi, np2, Tc=np2/(1+np2)); psiA[j] = psi.
// Hit test in pair: neg>0 requires nump>0 <=> dot > Tc*(1+nx2).
// ---------------------------------------------------------------------------
__global__ void prep_p(const float* __restrict__ p, unsigned short* __restrict__ pb,
                       const float* __restrict__ sum_x, const float* __restrict__ sum_nx2,
                       float4* __restrict__ colc, float* __restrict__ psiA,
                       int M, int N) {
  const int lane = threadIdx.x & 63;
  const int wave = threadIdx.x >> 6;
  const int j = blockIdx.x * 4 + wave;
  if (j >= M) return;
  const float2* p2 = (const float2*)p;
  ushort2* pb2 = (ushort2*)pb;
  float2 v = p2[j * 64 + lane];
  ushort2 b;
  b.x = f2bf(v.x);
  b.y = f2bf(v.y);
  pb2[j * 64 + lane] = b;
  float np2 = fmaf(v.x, v.x, v.y * v.y);
  float sd = fmaf(v.x, sum_x[2 * lane], v.y * sum_x[2 * lane + 1]);
#pragma unroll
  for (int off = 32; off; off >>= 1) {
    np2 += __shfl_down(np2, off);
    sd += __shfl_down(sd, off);
  }
  if (lane == 0) {
    float ssd = *sum_nx2 + (float)N * np2 - 2.f * sd;
    float npn = sqrtf(np2);
    float cfi = 1.f / (npn * sqrtf(ssd));
    float4 cc;
    cc.x = (1.f + np2) * cfi;
    cc.y = np2 * cfi;
    cc.z = np2;
    cc.w = np2 / (1.f + np2);
    colc[j] = cc;
    psiA[j] = asinf(KCONST * (1.f - np2) / npn);
  }
}

// ---------------------------------------------------------------------------
// pair_mfma: 128x128 tile/block; 4 waves in 2x2, each 64x64 (64 MFMA).
// Staging via global_load_lds width=16 with XOR-swizzled SOURCE permutation.
// Epilogue: exact early-out. neg>0 requires nump>0 <=> dot > Tc*(1+nx2); the
// common path is 1 fma + max-tree + cmp per element. Full rsqrt/acos runs in
// an exec-masked branch (dot-hit OR label column; expected ~2 taken
// group-iters per wave). Plain-store block partial.
// ---------------------------------------------------------------------------
__global__ __launch_bounds__(256, 2) void pair_mfma(
    const unsigned short* __restrict__ xb, const unsigned short* __restrict__ pb,
    const int* __restrict__ labels, const float* __restrict__ nx2,
    const float4* __restrict__ colc, const float* __restrict__ psiA,
    float* __restrict__ partials) {
  __shared__ float4 xs4[2048];  // 128 rows x 16 quads (quad = 8 bf16)
  __shared__ float4 ps4[2048];
  __shared__ float nxs[128];    // 1 + nx2
  __shared__ int lbs[128];
  __shared__ float wred[4];

  const int tid = threadIdx.x;
  const int l = tid & 63;
  const int w = tid >> 6;
  const int row0 = blockIdx.y * 128;
  const int col0 = blockIdx.x * 128;
  const float4* xg = (const float4*)(xb + (size_t)row0 * D_DIM);
  const float4* pg = (const float4*)(pb + (size_t)col0 * D_DIM);

  // stage A+B: LDS slot (r,ql) holds source quad (r, ql ^ (r&15))
#pragma unroll
  for (int ci = w; ci < 32; ci += 4) {
    int qi = ci * 64 + l;
    int r = qi >> 4, ql = qi & 15;
    int srcq = r * 16 + (ql ^ (r & 15));
    ASYNC_COPY16(xg + srcq, xs4 + ci * 64);
    ASYNC_COPY16(pg + srcq, ps4 + ci * 64);
  }
  if (tid < 128) {
    nxs[tid] = 1.f + nx2[row0 + tid];
    lbs[tid] = labels[row0 + tid];
  }
  __syncthreads();

  const int m = tid & 15;
  const int q = (tid >> 4) & 3;
  const int wr = (w & 1) * 64;   // wave's row offset within tile
  const int wc = (w >> 1) * 64;  // wave's col offset within tile

  f32x4 acc[4][4];
#pragma unroll
  for (int r = 0; r < 4; ++r)
#pragma unroll
    for (int c = 0; c < 4; ++c) acc[r][c] = (f32x4)(0.f);

#pragma unroll
  for (int s = 0; s < 4; ++s) {
    const int qphys = (s * 4 + q) ^ m;  // logical quad s*4+q, row low bits = m
    bf16x8 a[4], b[4];
#pragma unroll
    for (int r = 0; r < 4; ++r) {
      a[r] = __builtin_bit_cast(bf16x8, xs4[(wr + r * 16 + m) * 16 + qphys]);
      b[r] = __builtin_bit_cast(bf16x8, ps4[(wc + r * 16 + m) * 16 + qphys]);
    }
#pragma unroll
    for (int r = 0; r < 4; ++r)
#pragma unroll
      for (int c = 0; c < 4; ++c)
        acc[r][c] = __builtin_amdgcn_mfma_f32_16x16x32_bf16(a[r], b[c], acc[r][c], 0, 0, 0);
  }

  // ---- fused epilogue with exact early-out ----
  float4 cc[4];
  int cols[4];
#pragma unroll
  for (int c = 0; c < 4; ++c) {
    cols[c] = col0 + wc + c * 16 + m;
    cc[c] = colc[cols[c]];  // (Ac, Bc, np2, Tc)
  }

  float ssum = 0.f;
#pragma unroll
  for (int r = 0; r < 4; ++r) {
    const f32x4 rnp4 = __builtin_bit_cast(f32x4, *(const float4*)&nxs[wr + r * 16 + q * 4]);
    const int4 lb4 = *(const int4*)&lbs[wr + r * 16 + q * 4];
#pragma unroll
    for (int c = 0; c < 4; ++c) {
      const f32x4 dv = acc[r][c];
      const float Tc = cc[c].w;
      // e_g > 0  <=>  nump_g > 0  (necessary for any neg contribution)
      float e0 = fmaf(-Tc, rnp4[0], dv[0]);
      float e1 = fmaf(-Tc, rnp4[1], dv[1]);
      float e2 = fmaf(-Tc, rnp4[2], dv[2]);
      float e3 = fmaf(-Tc, rnp4[3], dv[3]);
      float hm = fmaxf(fmaxf(e0, e1), fmaxf(e2, e3));
      bool h = (hm > 0.f) | (cols[c] == lb4.x) | (cols[c] == lb4.y) |
               (cols[c] == lb4.z) | (cols[c] == lb4.w);
      if (__builtin_expect(h, 0)) {
        const float psi = psiA[cols[c]];
        const float C1 = 1.f + psi;
        const float omnp2 = 1.f - cc[c].z;
#pragma unroll
        for (int g = 0; g < 4; ++g) {
          float rnp = rnp4[g];
          float dot = dv[g];
          int lb = (g == 0) ? lb4.x : (g == 1) ? lb4.y : (g == 2) ? lb4.z : lb4.w;
          float den2 = fmaf(cc[c].z, rnp, omnp2) - 2.f * dot;
          float nump = fmaf(dot, cc[c].x, -cc[c].y * rnp);
          float u = nump * __builtin_amdgcn_rsqf(den2);
          u = __builtin_amdgcn_fmed3f(u, -1.f, 1.f);
          float ax = fabsf(u);
          float rt = __builtin_amdgcn_sqrtf(1.f - ax);
          float poly = fmaf(fmaf(fmaf(-0.0187293f, ax, 0.0742610f), ax, -0.2121144f),
                            ax, 1.5707288f);
          float ac = rt * poly;
          ac = (u >= 0.f) ? ac : 3.14159265358979f - ac;
          float neg = __builtin_amdgcn_fmed3f(C1 - ac, 0.f, 1.f);
          float pos = fmaxf(0.f, ac - psi);
          ssum += (cols[c] == lb) ? pos : neg;
        }
      }
    }
  }

#pragma unroll
  for (int off = 32; off; off >>= 1) ssum += __shfl_down(ssum, off);
  if (l == 0) wred[w] = ssum;
  __syncthreads();
  if (tid == 0)
    partials[blockIdx.y * gridDim.x + blockIdx.x] = wred[0] + wred[1] + wred[2] + wred[3];
}

// ---------------------------------------------------------------------------
// finalize: reduce the 2048 pair partials, scale by 1/N.
// ---------------------------------------------------------------------------
__global__ void finalize(const float* __restrict__ partials, float* __restrict__ out,
                         int n, float invN) {
  float s = 0.f;
  for (int i = threadIdx.x; i < n; i += 256) s += partials[i];
#pragma unroll
  for (int off = 32; off; off >>= 1) s += __shfl_down(s, off);
  __shared__ float wred[4];
  if ((threadIdx.x & 63) == 0) wred[threadIdx.x >> 6] = s;
  __syncthreads();
  if (threadIdx.x == 0) out[0] = (wred[0] + wred[1] + wred[2] + wred[3]) * invN;
}

extern "C" void kernel_launch(void* const* d_in, const int* in_sizes, int n_in,
                              void* d_out, int out_size, void* d_ws, size_t ws_size,
                              hipStream_t stream) {
  const float* x = (const float*)d_in[0];
  const float* p = (const float*)d_in[1];
  const int* labels = (const int*)d_in[2];
  float* out = (float*)d_out;
  const int N = in_sizes[2];          // 16384
  const int M = in_sizes[1] / D_DIM;  // 2048

  float* ws = (float*)d_ws;
  float* nx2 = ws;                                   // N
  float4* colc = (float4*)(ws + N);                  // M float4
  float* psiA = ws + N + 4 * M;                      // M
  unsigned short* xb = (unsigned short*)(ws + N + 5 * M);            // N*128 bf16
  unsigned short* pb = (unsigned short*)(ws + N + 5 * M + 64 * N);   // M*128 bf16
  float* pSumX = ws + N + 5 * M + 64 * N + 64 * M;   // 256*128
  float* pS2 = pSumX + 256 * 128;                    // 256
  float* sum_x = pS2 + 256;                          // 128
  float* sum_nx2 = sum_x + 128;                      // 4
  float* partials = sum_nx2 + 4;                     // 2048

  prep_x<<<256, 256, 0, stream>>>(x, xb, nx2, pSumX, pS2, N);
  merge_sums<<<1, 1024, 0, stream>>>(pSumX, pS2, sum_x, sum_nx2);
  prep_p<<<M / 4, 256, 0, stream>>>(p, pb, sum_x, sum_nx2, colc, psiA, M, N);

  dim3 grid(M / 128, N / 128);
  pair_mfma<<<grid, 256, 0, stream>>>(xb, pb, labels, nx2, colc, psiA, partials);

  finalize<<<1, 256, 0, stream>>>(partials, out, 2048, 1.0f / (float)N);
}